// Round 2
// baseline (218.102 us; speedup 1.0000x reference)
//
#include <hip/hip_runtime.h>
#include <stdint.h>

// Problem constants (static per reference)
#define NG    256    // graphs
#define NPG   128    // nodes per graph
#define PP    8      // perturbations
#define IND   64     // input dim
#define HID   128    // hidden
#define OUTD  10     // classes

typedef short bf16x8 __attribute__((ext_vector_type(8)));
typedef float f32x4  __attribute__((ext_vector_type(4)));

static __device__ __forceinline__ unsigned short f2bf(float f) {
    unsigned int u = __float_as_uint(f);
    u += 0x7FFFu + ((u >> 16) & 1u);
    return (unsigned short)(u >> 16);
}

static __device__ __forceinline__ f32x4 mfma16(bf16x8 a, bf16x8 b, f32x4 c) {
    return __builtin_amdgcn_mfma_f32_16x16x32_bf16(a, b, c, 0, 0, 0);
}

// Load 8 consecutive fp32 -> bf16x8 (B-operand fragment from global x)
static __device__ __forceinline__ bf16x8 cvt8(const float* __restrict__ p) {
    float4 lo = *(const float4*)p;
    float4 hi = *(const float4*)(p + 4);
    bf16x8 v;
    v[0] = (short)f2bf(lo.x); v[1] = (short)f2bf(lo.y);
    v[2] = (short)f2bf(lo.z); v[3] = (short)f2bf(lo.w);
    v[4] = (short)f2bf(hi.x); v[5] = (short)f2bf(hi.y);
    v[6] = (short)f2bf(hi.z); v[7] = (short)f2bf(hi.w);
    return v;
}

// ws layout (ushort elements):
//   [0)      W1t  128x64   (Wt[out][in])
//   [8192)   W2t  128x128
//   [24576)  Wg1t 128x128
//   [40960)  Wg2t 128x128
//   [57344)  Wb1t 128x128
//   [73728)  Wb2t 128x128
//   [90112)  agg  32768x128 bf16 (phase-A output)
#define AGG_OFF 90112

// ---------------------------------------------------------------------------
// Kernel 0: convert + transpose weights, COALESCED writes (strided reads stay
// in L2; total src is only 360 KB).
// ---------------------------------------------------------------------------
__global__ void prep_weights(const float* __restrict__ Wl1, const float* __restrict__ Wl2,
                             const float* __restrict__ Wg1, const float* __restrict__ Wg2,
                             const float* __restrict__ Wb1, const float* __restrict__ Wb2,
                             unsigned short* __restrict__ ws) {
    int e = blockIdx.x * blockDim.x + threadIdx.x;
    if (e < 8192) {
        // W1t[n][k] = Wl1[k][n], K=64
        int n = e >> 6, k = e & 63;
        ws[e] = f2bf(Wl1[k * HID + n]);
        return;
    }
    int e2 = e - 8192;
    int m = e2 >> 14;          // which 128x128 matrix
    int idx = e2 & 16383;
    int n = idx >> 7, k = idx & 127;
    const float* src;
    if      (m == 0) src = Wl2;
    else if (m == 1) src = Wg1;
    else if (m == 2) src = Wg2;
    else if (m == 3) src = Wb1;
    else             src = Wb2;
    ws[8192 + m * 16384 + idx] = f2bf(src[k * HID + n]);
}

#define LSTR 136   // LDS row stride in bf16 elements (272 B, 16 B aligned)

// ---------------------------------------------------------------------------
// Kernel 1 (phase A): block = (graph g, node-tile nt of 16 nodes). 2048 blocks
// x 256 threads (4 waves). Wave w owns out-tiles {2w, 2w+1}. For each of the 8
// perturbations: layer1 (K=64) from global x, layer2 (K=128) via LDS h1,
// relu-accumulate into per-lane agg regs; no atomics (all 8 p's local).
// Result written bf16 to aggbuf[node][128].
// ---------------------------------------------------------------------------
__global__ __launch_bounds__(256, 4) void local_mlp(
    const float* __restrict__ x,
    const unsigned short* __restrict__ wt,
    const float* __restrict__ bl1, const float* __restrict__ bl2,
    unsigned short* __restrict__ aggbuf)
{
    __shared__ unsigned short h1buf[2][16 * LSTR];

    const int g    = blockIdx.x >> 3;
    const int nt   = blockIdx.x & 7;
    const int tid  = threadIdx.x;
    const int wave = tid >> 6;
    const int lane = tid & 63;
    const int q    = lane >> 4;
    const int r    = lane & 15;
    const int ot0  = wave * 2;     // out-tiles ot0, ot0+1

    // weight fragments in registers for the whole kernel
    bf16x8 w1f[2][2];
#pragma unroll
    for (int t = 0; t < 2; ++t)
#pragma unroll
        for (int ks = 0; ks < 2; ++ks)
            w1f[t][ks] = *(const bf16x8*)(wt + ((ot0 + t) * 16 + r) * 64 + ks * 32 + q * 8);

    const unsigned short* w2t = wt + 8192;
    bf16x8 w2f[2][4];
#pragma unroll
    for (int t = 0; t < 2; ++t)
#pragma unroll
        for (int ks = 0; ks < 4; ++ks)
            w2f[t][ks] = *(const bf16x8*)(w2t + ((ot0 + t) * 16 + r) * 128 + ks * 32 + q * 8);

    // biases for this wave's 2 out-tiles (hoisted out of p-loop)
    float4 b1s[2], b2s[2];
#pragma unroll
    for (int t = 0; t < 2; ++t) {
        int ob = (ot0 + t) * 16 + q * 4;
        b1s[t] = *(const float4*)(bl1 + ob);
        b2s[t] = *(const float4*)(bl2 + ob);
    }

    f32x4 agg[2];
    agg[0] = (f32x4){0.f, 0.f, 0.f, 0.f};
    agg[1] = (f32x4){0.f, 0.f, 0.f, 0.f};

    const float* xg = x + (size_t)g * (NPG * PP) * IND;

    for (int p = 0; p < PP; ++p) {
        unsigned short* h1 = h1buf[p & 1];
        const int rowbase = p * 128 + nt * 16;

        // layer 1: K=64
        f32x4 acc[2];
        acc[0] = (f32x4){0.f, 0.f, 0.f, 0.f};
        acc[1] = (f32x4){0.f, 0.f, 0.f, 0.f};
#pragma unroll
        for (int ks = 0; ks < 2; ++ks) {
            bf16x8 xf = cvt8(xg + (rowbase + r) * IND + ks * 32 + q * 8);
            acc[0] = mfma16(w1f[0][ks], xf, acc[0]);
            acc[1] = mfma16(w1f[1][ks], xf, acc[1]);
        }
#pragma unroll
        for (int t = 0; t < 2; ++t) {
            int ob = (ot0 + t) * 16 + q * 4;
            ushort4 v;
            v.x = f2bf(fmaxf(acc[t][0] + b1s[t].x, 0.f));
            v.y = f2bf(fmaxf(acc[t][1] + b1s[t].y, 0.f));
            v.z = f2bf(fmaxf(acc[t][2] + b1s[t].z, 0.f));
            v.w = f2bf(fmaxf(acc[t][3] + b1s[t].w, 0.f));
            *(ushort4*)(h1 + r * LSTR + ob) = v;
        }
        __syncthreads();

        // layer 2: K=128, relu-accumulate into agg
        f32x4 acc2[2];
        acc2[0] = (f32x4){0.f, 0.f, 0.f, 0.f};
        acc2[1] = (f32x4){0.f, 0.f, 0.f, 0.f};
#pragma unroll
        for (int ks = 0; ks < 4; ++ks) {
            bf16x8 hf = *(const bf16x8*)(h1 + r * LSTR + ks * 32 + q * 8);
            acc2[0] = mfma16(w2f[0][ks], hf, acc2[0]);
            acc2[1] = mfma16(w2f[1][ks], hf, acc2[1]);
        }
#pragma unroll
        for (int t = 0; t < 2; ++t) {
            agg[t][0] += fmaxf(acc2[t][0] + b2s[t].x, 0.f);
            agg[t][1] += fmaxf(acc2[t][1] + b2s[t].y, 0.f);
            agg[t][2] += fmaxf(acc2[t][2] + b2s[t].z, 0.f);
            agg[t][3] += fmaxf(acc2[t][3] + b2s[t].w, 0.f);
        }
        // double-buffered h1 -> one barrier per p is sufficient
    }

    // store agg as bf16 to aggbuf[node][128]
    const int node = g * NPG + nt * 16 + r;
#pragma unroll
    for (int t = 0; t < 2; ++t) {
        int ob = (ot0 + t) * 16 + q * 4;
        ushort4 v;
        v.x = f2bf(agg[t][0]);
        v.y = f2bf(agg[t][1]);
        v.z = f2bf(agg[t][2]);
        v.w = f2bf(agg[t][3]);
        *(ushort4*)(aggbuf + (size_t)node * HID + ob) = v;
    }
}

// ---------------------------------------------------------------------------
// Kernel 2 (phase B+C): one block per graph, 512 threads = 8 waves.
// 4x (Linear+ReLU) on [128 nodes][128], pool, decoder, log_softmax.
// ---------------------------------------------------------------------------
__global__ __launch_bounds__(512, 2) void global_mlp(
    const unsigned short* __restrict__ wt,
    const unsigned short* __restrict__ aggbuf,
    const float* __restrict__ bg1, const float* __restrict__ bg2,
    const float* __restrict__ bb1, const float* __restrict__ bb2,
    const float* __restrict__ Wd1, const float* __restrict__ bd1,
    const float* __restrict__ Wd2, const float* __restrict__ bd2,
    float* __restrict__ out)
{
    __shared__ unsigned short buf0[128 * LSTR];
    __shared__ unsigned short buf1[128 * LSTR];
    __shared__ float pooled[HID];
    __shared__ float zbuf[80];

    const int g    = blockIdx.x;
    const int tid  = threadIdx.x;
    const int wave = tid >> 6;
    const int lane = tid & 63;
    const int q    = lane >> 4;
    const int r    = lane & 15;
    const int ot0  = (wave & 3) * 2;
    const int rt0  = (wave >> 2) * 4;

    if (tid < HID) pooled[tid] = 0.0f;

    // stage this graph's agg rows into buf0 (16 B chunks, coalesced)
    const unsigned short* ag = aggbuf + (size_t)g * NPG * HID;
    for (int c = tid; c < 2048; c += 512) {
        int row = c >> 4, cc = (c & 15) * 8;
        *(bf16x8*)(buf0 + row * LSTR + cc) = *(const bf16x8*)(ag + c * 8);
    }
    __syncthreads();

    int cur = 0;
#pragma unroll
    for (int l = 0; l < 4; ++l) {
        const unsigned short* wl = wt + 24576 + l * 16384;
        const float* bl = (l == 0) ? bg1 : (l == 1) ? bg2 : (l == 2) ? bb1 : bb2;

        bf16x8 wf[2][4];
#pragma unroll
        for (int t = 0; t < 2; ++t)
#pragma unroll
            for (int ks = 0; ks < 4; ++ks)
                wf[t][ks] = *(const bf16x8*)(wl + ((ot0 + t) * 16 + r) * 128 + ks * 32 + q * 8);

        unsigned short* Xb = cur ? buf1 : buf0;
        unsigned short* Yb = cur ? buf0 : buf1;

        f32x4 acc[2][4];
#pragma unroll
        for (int t = 0; t < 2; ++t)
#pragma unroll
            for (int j = 0; j < 4; ++j)
                acc[t][j] = (f32x4){0.f, 0.f, 0.f, 0.f};

#pragma unroll
        for (int ks = 0; ks < 4; ++ks) {
#pragma unroll
            for (int j = 0; j < 4; ++j) {
                int row = (rt0 + j) * 16 + r;
                bf16x8 xf = *(const bf16x8*)(Xb + row * LSTR + ks * 32 + q * 8);
                acc[0][j] = mfma16(wf[0][ks], xf, acc[0][j]);
                acc[1][j] = mfma16(wf[1][ks], xf, acc[1][j]);
            }
        }

        if (l < 3) {
#pragma unroll
            for (int t = 0; t < 2; ++t) {
                int ob = (ot0 + t) * 16 + q * 4;
                float4 bs = *(const float4*)(bl + ob);
#pragma unroll
                for (int j = 0; j < 4; ++j) {
                    int row = (rt0 + j) * 16 + r;
                    ushort4 v;
                    v.x = f2bf(fmaxf(acc[t][j][0] + bs.x, 0.f));
                    v.y = f2bf(fmaxf(acc[t][j][1] + bs.y, 0.f));
                    v.z = f2bf(fmaxf(acc[t][j][2] + bs.z, 0.f));
                    v.w = f2bf(fmaxf(acc[t][j][3] + bs.w, 0.f));
                    *(ushort4*)(Yb + row * LSTR + ob) = v;
                }
            }
            __syncthreads();
            cur ^= 1;
        } else {
            float s[2][4];
#pragma unroll
            for (int t = 0; t < 2; ++t) {
                int ob = (ot0 + t) * 16 + q * 4;
                float4 bs = *(const float4*)(bl + ob);
                s[t][0] = s[t][1] = s[t][2] = s[t][3] = 0.f;
#pragma unroll
                for (int j = 0; j < 4; ++j) {
                    s[t][0] += fmaxf(acc[t][j][0] + bs.x, 0.f);
                    s[t][1] += fmaxf(acc[t][j][1] + bs.y, 0.f);
                    s[t][2] += fmaxf(acc[t][j][2] + bs.z, 0.f);
                    s[t][3] += fmaxf(acc[t][j][3] + bs.w, 0.f);
                }
            }
#pragma unroll
            for (int m = 1; m < 16; m <<= 1) {
#pragma unroll
                for (int t = 0; t < 2; ++t)
#pragma unroll
                    for (int i = 0; i < 4; ++i)
                        s[t][i] += __shfl_xor(s[t][i], m, 64);
            }
            if (r == 0) {
#pragma unroll
                for (int t = 0; t < 2; ++t)
#pragma unroll
                    for (int i = 0; i < 4; ++i)
                        atomicAdd(&pooled[(ot0 + t) * 16 + q * 4 + i], s[t][i]);
            }
        }
    }
    __syncthreads();

    // decoder + log_softmax (fp32 VALU)
    if (tid < 64) {
        float a0 = bd1[tid], a1 = 0.f, a2 = 0.f, a3 = 0.f;
#pragma unroll
        for (int k = 0; k < 128; k += 4) {
            a0 += pooled[k]     * Wd1[(k)     * 64 + tid];
            a1 += pooled[k + 1] * Wd1[(k + 1) * 64 + tid];
            a2 += pooled[k + 2] * Wd1[(k + 2) * 64 + tid];
            a3 += pooled[k + 3] * Wd1[(k + 3) * 64 + tid];
        }
        zbuf[tid] = fmaxf((a0 + a1) + (a2 + a3), 0.f);
    }
    __syncthreads();
    if (tid < OUTD) {
        float a0 = bd2[tid], a1 = 0.f;
#pragma unroll
        for (int k = 0; k < 64; k += 2) {
            a0 += zbuf[k]     * Wd2[(k)     * OUTD + tid];
            a1 += zbuf[k + 1] * Wd2[(k + 1) * OUTD + tid];
        }
        zbuf[64 + tid] = a0 + a1;
    }
    __syncthreads();
    if (tid == 0) {
        float m = -1e30f;
#pragma unroll
        for (int j = 0; j < OUTD; ++j) m = fmaxf(m, zbuf[64 + j]);
        float ssum = 0.f;
#pragma unroll
        for (int j = 0; j < OUTD; ++j) ssum += expf(zbuf[64 + j] - m);
        float ls = logf(ssum);
#pragma unroll
        for (int j = 0; j < OUTD; ++j) out[g * OUTD + j] = zbuf[64 + j] - m - ls;
    }
}

extern "C" void kernel_launch(void* const* d_in, const int* in_sizes, int n_in,
                              void* d_out, int out_size, void* d_ws, size_t ws_size,
                              hipStream_t stream) {
    const float* x   = (const float*)d_in[0];
    // d_in[1] = ptr (unused; structure is static)
    const float* Wl1 = (const float*)d_in[2];
    const float* bl1 = (const float*)d_in[3];
    const float* Wl2 = (const float*)d_in[4];
    const float* bl2 = (const float*)d_in[5];
    const float* Wg1 = (const float*)d_in[6];
    const float* bg1 = (const float*)d_in[7];
    const float* Wg2 = (const float*)d_in[8];
    const float* bg2 = (const float*)d_in[9];
    const float* Wb1 = (const float*)d_in[10];
    const float* bb1 = (const float*)d_in[11];
    const float* Wb2 = (const float*)d_in[12];
    const float* bb2 = (const float*)d_in[13];
    const float* Wd1 = (const float*)d_in[14];
    const float* bd1 = (const float*)d_in[15];
    const float* Wd2 = (const float*)d_in[16];
    const float* bd2 = (const float*)d_in[17];

    unsigned short* ws  = (unsigned short*)d_ws;
    unsigned short* agg = ws + AGG_OFF;

    prep_weights<<<352, 256, 0, stream>>>(Wl1, Wl2, Wg1, Wg2, Wb1, Wb2, ws);
    local_mlp<<<NG * 8, 256, 0, stream>>>(x, ws, bl1, bl2, agg);
    global_mlp<<<NG, 512, 0, stream>>>(ws, agg, bg1, bg2, bb1, bb2,
                                       Wd1, bd1, Wd2, bd2, (float*)d_out);
}

// Round 3
// 159.385 us; speedup vs baseline: 1.3684x; 1.3684x over previous
//
#include <hip/hip_runtime.h>
#include <stdint.h>

// Problem constants (static per reference)
#define NG    256    // graphs
#define NPG   128    // nodes per graph
#define PP    8      // perturbations
#define IND   64     // input dim
#define HID   128    // hidden
#define OUTD  10     // classes

typedef short bf16x8 __attribute__((ext_vector_type(8)));
typedef float f32x4  __attribute__((ext_vector_type(4)));

static __device__ __forceinline__ unsigned short f2bf(float f) {
    unsigned int u = __float_as_uint(f);
    u += 0x7FFFu + ((u >> 16) & 1u);
    return (unsigned short)(u >> 16);
}

static __device__ __forceinline__ f32x4 mfma16(bf16x8 a, bf16x8 b, f32x4 c) {
    return __builtin_amdgcn_mfma_f32_16x16x32_bf16(a, b, c, 0, 0, 0);
}

// 8 consecutive fp32 -> bf16x8 (works for LDS or global generic pointers)
static __device__ __forceinline__ bf16x8 cvt8(const float* p) {
    float4 lo = *(const float4*)p;
    float4 hi = *(const float4*)(p + 4);
    bf16x8 v;
    v[0] = (short)f2bf(lo.x); v[1] = (short)f2bf(lo.y);
    v[2] = (short)f2bf(lo.z); v[3] = (short)f2bf(lo.w);
    v[4] = (short)f2bf(hi.x); v[5] = (short)f2bf(hi.y);
    v[6] = (short)f2bf(hi.z); v[7] = (short)f2bf(hi.w);
    return v;
}

// async global->LDS, 4 bytes per lane: lane i's 4B lands at lptr + lane*4
static __device__ __forceinline__ void async_load4(const float* gptr, float* lptr) {
    __builtin_amdgcn_global_load_lds(
        (const __attribute__((address_space(1))) unsigned int*)gptr,
        (__attribute__((address_space(3))) unsigned int*)lptr,
        4, 0, 0);
}

// ws layout:
//   shorts [0)      W1t  128x64   (Wt[out][in])
//   shorts [8192)   W2t  128x128
//   shorts [24576)  Wg1t 128x128
//   shorts [40960)  Wg2t 128x128
//   shorts [57344)  Wb1t 128x128
//   shorts [73728)  Wb2t 128x128
//   shorts [90112)  agg  32768x128 bf16 (phase-A output)
//   bytes  [8568832) partial 512x128 fp32 (half-graph pools)
#define AGG_OFF   90112
#define PART_BYTE 8568832

// ---------------------------------------------------------------------------
// Kernel 0: convert + transpose weights (coalesced writes; src stays in L2)
// ---------------------------------------------------------------------------
__global__ void prep_weights(const float* __restrict__ Wl1, const float* __restrict__ Wl2,
                             const float* __restrict__ Wg1, const float* __restrict__ Wg2,
                             const float* __restrict__ Wb1, const float* __restrict__ Wb2,
                             unsigned short* __restrict__ ws) {
    int e = blockIdx.x * blockDim.x + threadIdx.x;
    if (e < 8192) {
        int n = e >> 6, k = e & 63;
        ws[e] = f2bf(Wl1[k * HID + n]);
        return;
    }
    int e2 = e - 8192;
    int m = e2 >> 14;
    int idx = e2 & 16383;
    int n = idx >> 7, k = idx & 127;
    const float* src;
    if      (m == 0) src = Wl2;
    else if (m == 1) src = Wg1;
    else if (m == 2) src = Wg2;
    else if (m == 3) src = Wb1;
    else             src = Wb2;
    ws[8192 + m * 16384 + idx] = f2bf(src[k * HID + n]);
}

#define LSTR 136   // bf16 LDS row stride (272 B): 2-way bank aliasing only (free)
#define XSTR 68    // fp32 LDS row stride (272 B): same property

// ---------------------------------------------------------------------------
// Kernel 1 (phase A): block = (g, 16-node tile). 2048 blocks x 256 threads.
// All 8 perturbations' x rows (32 KB fp32) staged to LDS asynchronously up
// front (32 global_load_lds per wave -> ~96 KB in flight per CU); the p-loop
// is then pure LDS+MFMA. agg written back coalesced via LDS staging.
// ---------------------------------------------------------------------------
__global__ __launch_bounds__(256, 3) void local_mlp(
    const float* __restrict__ x,
    const unsigned short* __restrict__ wt,
    const float* __restrict__ bl1, const float* __restrict__ bl2,
    unsigned short* __restrict__ aggbuf)
{
    __shared__ float xbuf[128 * XSTR];                 // 34816 B
    __shared__ unsigned short h1buf[2][16 * LSTR];     //  8704 B

    const int g    = blockIdx.x >> 3;
    const int nt   = blockIdx.x & 7;
    const int tid  = threadIdx.x;
    const int wave = tid >> 6;
    const int lane = tid & 63;
    const int q    = lane >> 4;
    const int r    = lane & 15;
    const int ot0  = wave * 2;     // this wave's out-tiles

    // ---- issue all x staging first (row s = p*16+rr of the block's slab) ----
    {
        const float* xbase = x + ((size_t)g * 1024 + nt * 16) * IND + lane;
        for (int s = wave; s < 128; s += 4) {
            int p = s >> 4, rr = s & 15;
            async_load4(xbase + (size_t)(p * 128 + rr) * IND, &xbuf[s * XSTR]);
        }
    }

    // ---- weight fragments into registers (overlaps with x staging) ----
    bf16x8 w1f[2][2];
#pragma unroll
    for (int t = 0; t < 2; ++t)
#pragma unroll
        for (int ks = 0; ks < 2; ++ks)
            w1f[t][ks] = *(const bf16x8*)(wt + ((ot0 + t) * 16 + r) * 64 + ks * 32 + q * 8);

    const unsigned short* w2t = wt + 8192;
    bf16x8 w2f[2][4];
#pragma unroll
    for (int t = 0; t < 2; ++t)
#pragma unroll
        for (int ks = 0; ks < 4; ++ks)
            w2f[t][ks] = *(const bf16x8*)(w2t + ((ot0 + t) * 16 + r) * 128 + ks * 32 + q * 8);

    float4 b1s[2], b2s[2];
#pragma unroll
    for (int t = 0; t < 2; ++t) {
        int ob = (ot0 + t) * 16 + q * 4;
        b1s[t] = *(const float4*)(bl1 + ob);
        b2s[t] = *(const float4*)(bl2 + ob);
    }

    f32x4 agg[2];
    agg[0] = (f32x4){0.f, 0.f, 0.f, 0.f};
    agg[1] = (f32x4){0.f, 0.f, 0.f, 0.f};

    __syncthreads();   // drains vmcnt: all x rows now in LDS

    for (int p = 0; p < PP; ++p) {
        unsigned short* h1 = h1buf[p & 1];

        // layer 1 (K=64) from xbuf
        f32x4 acc[2];
        acc[0] = (f32x4){0.f, 0.f, 0.f, 0.f};
        acc[1] = (f32x4){0.f, 0.f, 0.f, 0.f};
#pragma unroll
        for (int ks = 0; ks < 2; ++ks) {
            bf16x8 xf = cvt8(&xbuf[(p * 16 + r) * XSTR + ks * 32 + q * 8]);
            acc[0] = mfma16(w1f[0][ks], xf, acc[0]);
            acc[1] = mfma16(w1f[1][ks], xf, acc[1]);
        }
#pragma unroll
        for (int t = 0; t < 2; ++t) {
            int ob = (ot0 + t) * 16 + q * 4;
            ushort4 v;
            v.x = f2bf(fmaxf(acc[t][0] + b1s[t].x, 0.f));
            v.y = f2bf(fmaxf(acc[t][1] + b1s[t].y, 0.f));
            v.z = f2bf(fmaxf(acc[t][2] + b1s[t].z, 0.f));
            v.w = f2bf(fmaxf(acc[t][3] + b1s[t].w, 0.f));
            *(ushort4*)(h1 + r * LSTR + ob) = v;
        }
        __syncthreads();

        // layer 2 (K=128), relu-accumulate into agg
        f32x4 acc2[2];
        acc2[0] = (f32x4){0.f, 0.f, 0.f, 0.f};
        acc2[1] = (f32x4){0.f, 0.f, 0.f, 0.f};
#pragma unroll
        for (int ks = 0; ks < 4; ++ks) {
            bf16x8 hf = *(const bf16x8*)(h1 + r * LSTR + ks * 32 + q * 8);
            acc2[0] = mfma16(w2f[0][ks], hf, acc2[0]);
            acc2[1] = mfma16(w2f[1][ks], hf, acc2[1]);
        }
#pragma unroll
        for (int t = 0; t < 2; ++t) {
            agg[t][0] += fmaxf(acc2[t][0] + b2s[t].x, 0.f);
            agg[t][1] += fmaxf(acc2[t][1] + b2s[t].y, 0.f);
            agg[t][2] += fmaxf(acc2[t][2] + b2s[t].z, 0.f);
            agg[t][3] += fmaxf(acc2[t][3] + b2s[t].w, 0.f);
        }
        // double-buffered h1 -> one barrier per p is sufficient
    }

    // stage agg (bf16) in h1buf[0]; safe without a barrier (p=7 barrier already
    // guarantees every wave finished its buf0 reads of p=6)
#pragma unroll
    for (int t = 0; t < 2; ++t) {
        int ob = (ot0 + t) * 16 + q * 4;
        ushort4 v;
        v.x = f2bf(agg[t][0]);
        v.y = f2bf(agg[t][1]);
        v.z = f2bf(agg[t][2]);
        v.w = f2bf(agg[t][3]);
        *(ushort4*)(h1buf[0] + r * LSTR + ob) = v;
    }
    __syncthreads();

    // coalesced writeback: 256 threads x 16 B = one full 4 KB tile
    {
        int row = tid >> 4, c8 = (tid & 15) * 8;
        bf16x8 v = *(const bf16x8*)(h1buf[0] + row * LSTR + c8);
        *(bf16x8*)(aggbuf + ((size_t)(g * NPG + nt * 16 + row)) * HID + c8) = v;
    }
}

// ---------------------------------------------------------------------------
// Kernel 2: 4x (Linear+ReLU) on half-graphs (64 rows). 512 blocks x 256 thr.
// Wave w owns output columns [32w, 32w+32) -> atomic-free partial pool.
// ---------------------------------------------------------------------------
__global__ __launch_bounds__(256, 3) void global_layers(
    const unsigned short* __restrict__ wt,
    const unsigned short* __restrict__ aggbuf,
    const float* __restrict__ bg1, const float* __restrict__ bg2,
    const float* __restrict__ bb1, const float* __restrict__ bb2,
    float* __restrict__ partial)
{
    __shared__ unsigned short buf0[64 * LSTR];
    __shared__ unsigned short buf1[64 * LSTR];
    __shared__ float pool[HID];

    const int g    = blockIdx.x >> 1;
    const int h    = blockIdx.x & 1;
    const int tid  = threadIdx.x;
    const int wave = tid >> 6;
    const int lane = tid & 63;
    const int q    = lane >> 4;
    const int r    = lane & 15;
    const int ot0  = wave * 2;

    // stage this half-graph's 64 agg rows (16 KB) coalesced
    const unsigned short* ag = aggbuf + ((size_t)g * NPG + h * 64) * HID;
#pragma unroll
    for (int it = 0; it < 4; ++it) {
        int c = tid + it * 256;
        int row = c >> 4, c8 = (c & 15) * 8;
        *(bf16x8*)(buf0 + row * LSTR + c8) = *(const bf16x8*)(ag + (size_t)row * HID + c8);
    }
    __syncthreads();

    int cur = 0;
#pragma unroll
    for (int l = 0; l < 4; ++l) {
        const unsigned short* wl = wt + 24576 + l * 16384;
        const float* bl = (l == 0) ? bg1 : (l == 1) ? bg2 : (l == 2) ? bb1 : bb2;

        bf16x8 wf[2][4];
#pragma unroll
        for (int t = 0; t < 2; ++t)
#pragma unroll
            for (int ks = 0; ks < 4; ++ks)
                wf[t][ks] = *(const bf16x8*)(wl + ((ot0 + t) * 16 + r) * 128 + ks * 32 + q * 8);

        unsigned short* Xb = cur ? buf1 : buf0;
        unsigned short* Yb = cur ? buf0 : buf1;

        f32x4 acc[2][4];
#pragma unroll
        for (int t = 0; t < 2; ++t)
#pragma unroll
            for (int j = 0; j < 4; ++j)
                acc[t][j] = (f32x4){0.f, 0.f, 0.f, 0.f};

#pragma unroll
        for (int ks = 0; ks < 4; ++ks) {
#pragma unroll
            for (int j = 0; j < 4; ++j) {
                int row = j * 16 + r;
                bf16x8 xf = *(const bf16x8*)(Xb + row * LSTR + ks * 32 + q * 8);
                acc[0][j] = mfma16(wf[0][ks], xf, acc[0][j]);
                acc[1][j] = mfma16(wf[1][ks], xf, acc[1][j]);
            }
        }

        if (l < 3) {
#pragma unroll
            for (int t = 0; t < 2; ++t) {
                int ob = (ot0 + t) * 16 + q * 4;
                float4 bs = *(const float4*)(bl + ob);
#pragma unroll
                for (int j = 0; j < 4; ++j) {
                    int row = j * 16 + r;
                    ushort4 v;
                    v.x = f2bf(fmaxf(acc[t][j][0] + bs.x, 0.f));
                    v.y = f2bf(fmaxf(acc[t][j][1] + bs.y, 0.f));
                    v.z = f2bf(fmaxf(acc[t][j][2] + bs.z, 0.f));
                    v.w = f2bf(fmaxf(acc[t][j][3] + bs.w, 0.f));
                    *(ushort4*)(Yb + row * LSTR + ob) = v;
                }
            }
            __syncthreads();
            cur ^= 1;
        } else {
            float s[2][4];
#pragma unroll
            for (int t = 0; t < 2; ++t) {
                int ob = (ot0 + t) * 16 + q * 4;
                float4 bs = *(const float4*)(bl + ob);
                s[t][0] = s[t][1] = s[t][2] = s[t][3] = 0.f;
#pragma unroll
                for (int j = 0; j < 4; ++j) {
                    s[t][0] += fmaxf(acc[t][j][0] + bs.x, 0.f);
                    s[t][1] += fmaxf(acc[t][j][1] + bs.y, 0.f);
                    s[t][2] += fmaxf(acc[t][j][2] + bs.z, 0.f);
                    s[t][3] += fmaxf(acc[t][j][3] + bs.w, 0.f);
                }
            }
#pragma unroll
            for (int m = 1; m < 16; m <<= 1) {
#pragma unroll
                for (int t = 0; t < 2; ++t)
#pragma unroll
                    for (int i = 0; i < 4; ++i)
                        s[t][i] += __shfl_xor(s[t][i], m, 64);
            }
            if (r == 0) {
#pragma unroll
                for (int t = 0; t < 2; ++t)
#pragma unroll
                    for (int i = 0; i < 4; ++i)
                        pool[(ot0 + t) * 16 + q * 4 + i] = s[t][i];  // exclusive cols/wave
            }
        }
    }
    __syncthreads();
    if (tid < HID) partial[(size_t)blockIdx.x * HID + tid] = pool[tid];
}

// ---------------------------------------------------------------------------
// Kernel 3: decoder + log_softmax. 256 blocks x 64 threads.
// ---------------------------------------------------------------------------
__global__ void decoder_k(const float* __restrict__ partial,
                          const float* __restrict__ Wd1, const float* __restrict__ bd1,
                          const float* __restrict__ Wd2, const float* __restrict__ bd2,
                          float* __restrict__ out)
{
    __shared__ float pooled[HID];
    __shared__ float z[64];
    __shared__ float zz[OUTD];

    const int g = blockIdx.x;
    const int t = threadIdx.x;

    const float* p0 = partial + (size_t)(2 * g) * HID;
    const float* p1 = p0 + HID;
    pooled[t]      = p0[t]      + p1[t];
    pooled[t + 64] = p0[t + 64] + p1[t + 64];
    __syncthreads();

    float a0 = bd1[t], a1 = 0.f, a2 = 0.f, a3 = 0.f;
#pragma unroll
    for (int k = 0; k < 128; k += 4) {
        a0 += pooled[k]     * Wd1[(k)     * 64 + t];
        a1 += pooled[k + 1] * Wd1[(k + 1) * 64 + t];
        a2 += pooled[k + 2] * Wd1[(k + 2) * 64 + t];
        a3 += pooled[k + 3] * Wd1[(k + 3) * 64 + t];
    }
    z[t] = fmaxf((a0 + a1) + (a2 + a3), 0.f);
    __syncthreads();

    if (t < OUTD) {
        float b0 = bd2[t], b1 = 0.f;
#pragma unroll
        for (int k = 0; k < 64; k += 2) {
            b0 += z[k]     * Wd2[(k)     * OUTD + t];
            b1 += z[k + 1] * Wd2[(k + 1) * OUTD + t];
        }
        zz[t] = b0 + b1;
    }
    __syncthreads();
    if (t == 0) {
        float m = -1e30f;
#pragma unroll
        for (int j = 0; j < OUTD; ++j) m = fmaxf(m, zz[j]);
        float ssum = 0.f;
#pragma unroll
        for (int j = 0; j < OUTD; ++j) ssum += expf(zz[j] - m);
        float ls = logf(ssum);
#pragma unroll
        for (int j = 0; j < OUTD; ++j) out[g * OUTD + j] = zz[j] - m - ls;
    }
}

extern "C" void kernel_launch(void* const* d_in, const int* in_sizes, int n_in,
                              void* d_out, int out_size, void* d_ws, size_t ws_size,
                              hipStream_t stream) {
    const float* x   = (const float*)d_in[0];
    // d_in[1] = ptr (unused; structure is static)
    const float* Wl1 = (const float*)d_in[2];
    const float* bl1 = (const float*)d_in[3];
    const float* Wl2 = (const float*)d_in[4];
    const float* bl2 = (const float*)d_in[5];
    const float* Wg1 = (const float*)d_in[6];
    const float* bg1 = (const float*)d_in[7];
    const float* Wg2 = (const float*)d_in[8];
    const float* bg2 = (const float*)d_in[9];
    const float* Wb1 = (const float*)d_in[10];
    const float* bb1 = (const float*)d_in[11];
    const float* Wb2 = (const float*)d_in[12];
    const float* bb2 = (const float*)d_in[13];
    const float* Wd1 = (const float*)d_in[14];
    const float* bd1 = (const float*)d_in[15];
    const float* Wd2 = (const float*)d_in[16];
    const float* bd2 = (const float*)d_in[17];

    unsigned short* ws   = (unsigned short*)d_ws;
    unsigned short* agg  = ws + AGG_OFF;
    float* partial       = (float*)((char*)d_ws + PART_BYTE);

    prep_weights<<<352, 256, 0, stream>>>(Wl1, Wl2, Wg1, Wg2, Wb1, Wb2, ws);
    local_mlp<<<NG * 8, 256, 0, stream>>>(x, ws, bl1, bl2, agg);
    global_layers<<<NG * 2, 256, 0, stream>>>(ws, agg, bg1, bg2, bb1, bb2, partial);
    decoder_k<<<NG, 64, 0, stream>>>(partial, Wd1, bd1, Wd2, bd2, (float*)d_out);
}